// Round 10
// baseline (124.900 us; speedup 1.0000x reference)
//
#include <hip/hip_runtime.h>
#include <math.h>

// ConnectedLossV4, 3-node graph. R6: per-node boundary cost (~8-11us) dominated
// (7 nodes, ~50us work, 125us total). Fused to 3 kernels; arrive+spin grid
// barriers only where co-residency is provable (__launch_bounds__(256,2) =>
// >=2 blocks/CU => 512 blocks co-resident). Cross-block data inside a fused
// kernel must use agent-scope atomic ld/st (LLC coherence point) -- R7 bug #2:
// plain path-halving stores sat dirty in per-XCD L2 and could write back AFTER
// flatten's root stores (arbitrary flush order across XCDs) -> halving stores
// are now AS (relaxed atomic, straight to LLC, drained by __syncthreads before
// the barrier). R7 bug #1: k_uf got nbam=512 but 1024 partials exist -> half
// the counts were dropped. Fixed: nbam=1024 everywhere.
//   1 k_argmax  block0 zeros stats+ghist; argmax + bg-bce/dice continuous part;
//               per-block partial counts/doubles via PLAIN stores (no atomics
//               -> nothing needs pre-zeroing); parent/pk init.
//   2 k_uf      merge (CAS union-find, atomic halving) -> arrive+spin barrier
//               -> flatten (read-only chase via atomic loads; single-writer
//               root stores) -> arrive -> last block reduces partials + scalars.
//   3 k_phase2  placeholder keys in REGISTERS (2 quads/thread), anchored 8-bit
//               radix pass 1 into per-(blockIdx&7) ghist replica -> arrive ->
//               last block scans -> release flag -> spin -> [rare fallback
//               passes] -> median-match counts from registers -> arrive ->
//               last block closed-form bce+dice -> out.
//
// ws layout (N = B*H*W = 1048576):
//   [0,4N) parent | [4N,5N) pk = cls|tgt<<3 | [5N,..) stats/ghist/partials
// stats words: 8..15 cntTarget totals, 16..23 ncomp, 24..31 prodf bits,
//   32 pb, 33 ab, 34 nA, 35 nB, 36 ph0 bits, 37 s1, 38 resolved, 39 radix
//   progress flag, 40..47 median-offset prefix, 48..55 krem, 56..63 n11,
//   64..71 nfm, arrivals: 76 merge, 85 flatten, 77 hist1, 78/79/80 passes,
//   84 med; 90 merge flag.
//   ghist = stats+8192 (8 replicas x 7 x 256 = 14336 words)
//   pcnt  = stats+22528 (1024 blocks x 20 words: cls[8], tgt[8], nA, nB, pad)
//   pdbl  = (double*)(stats+43008) (1024 x 3 doubles)

#define HWMASK (262144 - 1)
#define AL(p) __hip_atomic_load((p), __ATOMIC_RELAXED, __HIP_MEMORY_SCOPE_AGENT)
#define AS(p, v) __hip_atomic_store((p), (v), __ATOMIC_RELAXED, __HIP_MEMORY_SCOPE_AGENT)
#define REL(p, v) __hip_atomic_store((p), (v), __ATOMIC_RELEASE, __HIP_MEMORY_SCOPE_AGENT)
#define ARRIVE(p) __hip_atomic_fetch_add((p), 1u, __ATOMIC_RELAXED, __HIP_MEMORY_SCOPE_AGENT)

// Merge-phase find: plain reads are fine (CAS re-verifies against LLC truth),
// but the halving store MUST be atomic: a plain store can sit dirty in this
// XCD's L2 and write back over flatten's root store after the barrier.
static __device__ __forceinline__ int ufind(int* p, int x) {
  while (true) {
    int px = p[x];
    if (px == x) return x;
    int g = p[px];
    if (g == px) return px;
    AS(&p[x], g);  // path halving -> LLC (g is an ancestor: benign race)
    x = g;
  }
}

static __device__ __forceinline__ void unite(int* p, int a, int b) {
  while (true) {
    a = ufind(p, a); b = ufind(p, b);
    if (a == b) return;
    if (a < b) { int old = atomicCAS(&p[b], b, a); if (old == b) return; b = old; }
    else       { int old = atomicCAS(&p[a], a, b); if (old == a) return; a = old; }
  }
}

__global__ __launch_bounds__(256) void k_argmax(
    const float* __restrict__ pred, const int* __restrict__ tgt,
    int* __restrict__ parent, unsigned char* __restrict__ pk,
    unsigned* __restrict__ stats, unsigned* __restrict__ pcnt,
    double* __restrict__ pdbl, int N) {
  __shared__ unsigned hc[32], ht[32], hA, hB;   // per-wave banks (4 waves x 8)
  __shared__ double dred[12];
  int tid = threadIdx.x, bid = blockIdx.x;
  if (bid == 0) {     // zero stats+ghist; no other block touches them here
    uint4* z = (uint4*)stats;
    for (int j = tid; j < 5632; j += 256) z[j] = make_uint4(0u, 0u, 0u, 0u);
  }
  if (tid < 32) { hc[tid] = 0; ht[tid] = 0; }
  if (tid == 0) { hA = 0; hB = 0; }
  __syncthreads();
  int wb = (tid >> 6) << 3;     // wave bank base
  int n4 = N >> 2, gsz = gridDim.x * blockDim.x;
  double aL = 0.0, aI = 0.0, aP = 0.0;
  unsigned nA = 0, nB = 0;
  for (int i4 = bid * blockDim.x + tid; i4 < n4; i4 += gsz) {
    int i = i4 << 2;
    int b = i >> 18, hw = i & HWMASK;
    const float* pp = pred + ((size_t)b << 21) + hw;
    float4 v[8];
#pragma unroll
    for (int ch = 0; ch < 8; ++ch) v[ch] = *(const float4*)(pp + ((size_t)ch << 18));
    int4 tv = *(const int4*)(tgt + i);
    int tarr[4] = {tv.x & 7, tv.y & 7, tv.z & 7, tv.w & 7};
    unsigned char pkb[4];
#pragma unroll
    for (int j = 0; j < 4; ++j) {
      float p0 = ((const float*)&v[0])[j];
      float best = p0; int c = 0;
#pragma unroll
      for (int ch = 1; ch < 8; ++ch) {          // first-max == numpy argmax
        float x = ((const float*)&v[ch])[j];
        if (x > best) { best = x; c = ch; }
      }
      int t = tarr[j];
      pkb[j] = (unsigned char)(c | (t << 3));
      atomicAdd(&hc[wb + c], 1u);
      atomicAdd(&ht[wb + t], 1u);
      if (c == 0) {                             // continuous bg term
        float pc = fminf(fmaxf(p0, 1e-7f), 1.0f - 1e-7f);
        if (t == 0) { aL += (double)logf(pc); aI += (double)p0; }
        else        { aL += (double)logf(1.0f - pc); }
        aP += (double)p0;
      } else { if (t == 0) nA++; else nB++; }   // pv==0 -> constant log, count
    }
    *(int4*)(parent + i) = make_int4(i, i + 1, i + 2, i + 3);
    *(uchar4*)(pk + i) = make_uchar4(pkb[0], pkb[1], pkb[2], pkb[3]);
  }
  if (nA) atomicAdd(&hA, nA);
  if (nB) atomicAdd(&hB, nB);
#pragma unroll
  for (int o = 32; o > 0; o >>= 1) {
    aL += __shfl_down(aL, o); aI += __shfl_down(aI, o); aP += __shfl_down(aP, o);
  }
  int wid = tid >> 6, lane = tid & 63;
  if (lane == 0) { dred[wid] = aL; dred[4 + wid] = aI; dred[8 + wid] = aP; }
  __syncthreads();
  // per-block partials: plain stores, every slot written -> no pre-zero needed
  if (tid < 8) {
    pcnt[bid * 20 + tid]     = hc[tid] + hc[8 + tid] + hc[16 + tid] + hc[24 + tid];
    pcnt[bid * 20 + 8 + tid] = ht[tid] + ht[8 + tid] + ht[16 + tid] + ht[24 + tid];
  }
  if (tid == 0) {
    pcnt[bid * 20 + 16] = hA; pcnt[bid * 20 + 17] = hB;
    pcnt[bid * 20 + 18] = 0u; pcnt[bid * 20 + 19] = 0u;
    pdbl[bid * 3 + 0] = dred[0] + dred[1] + dred[2] + dred[3];
    pdbl[bid * 3 + 1] = dred[4] + dred[5] + dred[6] + dred[7];
    pdbl[bid * 3 + 2] = dred[8] + dred[9] + dred[10] + dred[11];
  }
}

__global__ __launch_bounds__(256, 2) void k_uf(
    const unsigned char* __restrict__ pk, int* __restrict__ parent,
    unsigned* __restrict__ stats, const unsigned* __restrict__ pcnt,
    int N, int nbam) {
  __shared__ unsigned nc[8], tot[18];
  __shared__ int lastF;
  int tid = threadIdx.x;
  int n4 = N >> 2, gsz = gridDim.x * blockDim.x;
  // ---- merge ------------------------------------------------------------
  for (int i4 = blockIdx.x * blockDim.x + tid; i4 < n4; i4 += gsz) {
    int i = i4 << 2;
    int hw = i & HWMASK;
    uchar4 a = *(const uchar4*)(pk + i);
    unsigned char ca[4] = {(unsigned char)(a.x & 7), (unsigned char)(a.y & 7),
                           (unsigned char)(a.z & 7), (unsigned char)(a.w & 7)};
    if (ca[0] && ca[0] == ca[1]) unite(parent, i,     i + 1);
    if (ca[1] && ca[1] == ca[2]) unite(parent, i + 1, i + 2);
    if (ca[2] && ca[2] == ca[3]) unite(parent, i + 2, i + 3);
    if ((hw & 511) < 508) {
      unsigned char nx = pk[i + 4] & 7;
      if (ca[3] && ca[3] == nx) unite(parent, i + 3, i + 4);
    }
    if ((hw >> 9) < 511) {
      uchar4 d = *(const uchar4*)(pk + i + 512);
      unsigned char da[4] = {(unsigned char)(d.x & 7), (unsigned char)(d.y & 7),
                             (unsigned char)(d.z & 7), (unsigned char)(d.w & 7)};
#pragma unroll
      for (int j = 0; j < 4; ++j)
        if (ca[j] && ca[j] == da[j]) unite(parent, i + j, i + j + 512);
    }
  }
  __syncthreads();   // drains vmcnt -> this block's CAS/AS complete at LLC
  // ---- arrive+spin grid barrier (co-residency: launch_bounds(256,2)) -----
  if (tid == 0) {
    if (ARRIVE(&stats[76]) == gridDim.x - 1) REL(&stats[90], 1u);
    else while (AL(&stats[90]) == 0u) __builtin_amdgcn_s_sleep(2);
  }
  __syncthreads();
  // ---- flatten: atomic loads (no boundary flush inside a fused kernel) ---
  if (tid < 8) nc[tid] = 0;
  __syncthreads();
  for (int i4 = blockIdx.x * blockDim.x + tid; i4 < n4; i4 += gsz) {
    int i = i4 << 2;
    uchar4 a = *(const uchar4*)(pk + i);
    unsigned char ca[4] = {(unsigned char)(a.x & 7), (unsigned char)(a.y & 7),
                           (unsigned char)(a.z & 7), (unsigned char)(a.w & 7)};
    int pa[4];
#pragma unroll
    for (int j = 0; j < 4; ++j) {
      pa[j] = i + j;
      if (!ca[j]) continue;
      int x = AL(&parent[i + j]);
      if (x == i + j) { atomicAdd(&nc[ca[j]], 1u); continue; }  // representative
      // read-only chase via coherent loads; values only ever move toward root
      while (true) { int nx = AL(&parent[x]); if (nx == x) break; x = nx; }
      pa[j] = x;
    }
    *(int4*)(parent + i) = make_int4(pa[0], pa[1], pa[2], pa[3]);
  }
  __syncthreads();
  if (tid < 8 && nc[tid]) atomicAdd(&stats[16 + tid], nc[tid]);
  __syncthreads();
  if (tid == 0) lastF = (ARRIVE(&stats[85]) == gridDim.x - 1) ? 1 : 0;
  __syncthreads();
  if (!lastF) return;
  // ---- last block: reduce partials (ALL nbam=1024 of them) ---------------
  unsigned S[18];
#pragma unroll
  for (int k = 0; k < 18; ++k) S[k] = 0u;
  for (int b = tid; b < nbam; b += 256) {
    const unsigned* p = pcnt + b * 20;
#pragma unroll
    for (int k = 0; k < 18; ++k) S[k] += p[k];
  }
  if (tid < 18) tot[tid] = 0u;
  __syncthreads();
#pragma unroll
  for (int k = 0; k < 18; ++k) {
    unsigned s = S[k];
#pragma unroll
    for (int o = 32; o > 0; o >>= 1) s += __shfl_down(s, o);
    if ((tid & 63) == 0 && s) atomicAdd(&tot[k], s);
  }
  __syncthreads();
  if (tid != 0) return;
  // ---- scalars (single thread) ------------------------------------------
  float prodf[8]; int last_i = 1; unsigned pb = 0;
  for (int v = 1; v < 8; ++v) {
    unsigned cntv = tot[v], ncv = AL(&stats[16 + v]);
    prodf[v] = 0.0f;
    if (cntv) {
      prodf[v] = __fmul_rn((float)ncv, (float)last_i);   // exact ref rounding
      pb |= 1u << v;
      last_i += (int)ncv + ((cntv < (unsigned)N) ? 1 : 0);  // + has_bg
    }
    stats[24 + v] = __float_as_uint(prodf[v]);
  }
  float ph0 = 0.0f;   // background key (min key: rounding is monotone)
  for (int v = 1; v < 8; ++v) if (pb & (1u << v)) ph0 = __fadd_rn(ph0, prodf[v]);
  unsigned ab = 0;
  for (int t = 1; t < 8; ++t) {
    unsigned n = tot[8 + t];
    stats[8 + t] = n;
    ((int*)stats)[48 + t] = n ? (int)((n - 1) >> 1) : -1;   // lower-median rank
    if (n) ab |= 1u << t;
  }
  stats[8] = tot[8];
  stats[34] = tot[16]; stats[35] = tot[17];
  stats[32] = pb; stats[33] = ab;
  unsigned pbits = __float_as_uint(ph0);
  stats[36] = pbits;
  // key-code window bound: codes in (ph0, ph0+2^20] <= 2^(43-e), e=exp(ph0)
  unsigned c;
  if (pbits == 0) c = 64u;
  else {
    int e = (int)(pbits >> 23) - 127;
    int sh = 43 - e;
    if (sh <= 0) c = 64u;
    else if (sh >= 31) c = 0x7FFFFFFFu;
    else c = (1u << sh) + 64u;
  }
  int bl = 32 - __clz((int)c);
  stats[37] = (bl > 8) ? (unsigned)(bl - 8) : 0u;   // s1 for 8-bit digits
}

// Sum 8 ghist replicas, scan 256 bins, pick the bin holding rank krem[t].
static __device__ void scan_select(unsigned* __restrict__ stats,
                                   const unsigned* __restrict__ ghist,
                                   unsigned abm, int s_cur, unsigned* lh) {
  int tid = threadIdx.x;
  for (int t = 1; t < 8; ++t) {
    if (!(abm >> t & 1u)) continue;
    int k = (int)AL(&stats[48 + t]);
    unsigned cnt = 0;
#pragma unroll
    for (int r = 0; r < 8; ++r)
      cnt += AL(&ghist[r * 1792 + ((t - 1) << 8) + tid]);
    lh[tid] = cnt;
    __syncthreads();
    for (int o = 1; o < 256; o <<= 1) {   // inclusive Hillis-Steele
      unsigned v = (tid >= o) ? lh[tid - o] : 0u;
      __syncthreads();
      lh[tid] += v;
      __syncthreads();
    }
    unsigned incl = lh[tid], excl = incl - cnt;
    if ((unsigned)k >= excl && (unsigned)k < incl) {   // unique owner
      atomicOr(&stats[40 + t], ((unsigned)tid) << s_cur);
      AS(&stats[48 + t], (unsigned)(k - (int)excl));
    }
    __syncthreads();
  }
}

__global__ __launch_bounds__(256, 2) void k_phase2(
    const unsigned char* __restrict__ pk, const int* __restrict__ parent,
    unsigned* __restrict__ stats, unsigned* __restrict__ ghist,
    const double* __restrict__ pdbl, float* __restrict__ out, int N, int nbam) {
  __shared__ unsigned lh[1792];
  __shared__ float sprod[8];
  __shared__ unsigned sw[32];
  __shared__ double dred[12];
  int tid = threadIdx.x;
  if (tid < 8) sprod[tid] = __uint_as_float(stats[24 + tid]);
  if (tid == 0) { sw[0] = stats[32]; sw[1] = stats[33]; sw[2] = stats[36]; sw[3] = stats[37]; }
  for (int j = tid; j < 1792; j += 256) lh[j] = 0u;
  __syncthreads();
  unsigned pb = sw[0], ab = sw[1], ph0 = sw[2];
  int s1 = (int)sw[3];
  unsigned rep = (blockIdx.x & 7) * 1792u;
  int n4 = N >> 2, gsz = gridDim.x * blockDim.x;
  // ---- keys in registers + radix pass 1 ---------------------------------
  unsigned kk[8];
  unsigned char tv8[8];
#pragma unroll
  for (int q = 0; q < 2; ++q) {
    int i4 = blockIdx.x * blockDim.x + tid + q * gsz;
    if (i4 < n4) {
      int i = i4 << 2;
      int4 pr = *(const int4*)(parent + i);
      uchar4 pv = *(const uchar4*)(pk + i);
      int parr[4] = {pr.x, pr.y, pr.z, pr.w};
      unsigned char pa[4] = {pv.x, pv.y, pv.z, pv.w};
#pragma unroll
      for (int j = 0; j < 4; ++j) {
        int c = pa[j] & 7, t = pa[j] >> 3;
        float lab = c ? (float)(parr[j] + 1) : 0.0f;   // < 2^24, exact
        float ph = 0.0f;
#pragma unroll
        for (int v = 1; v < 8; ++v) {                  // exact numpy op order
          if (pb & (1u << v)) {
            float term = sprod[v];
            if (c == v) term = __fadd_rn(lab, term);
            ph = __fadd_rn(ph, term);
          }
        }
        unsigned kb = __float_as_uint(ph);
        kk[q * 4 + j] = kb; tv8[q * 4 + j] = (unsigned char)t;
        if (t && (ab >> t & 1u)) {
          unsigned off = kb - ph0;                     // >= 0 by monotonicity
          unsigned bin = off >> s1;
          if (bin > 255u) bin = 255u;
          atomicAdd(&lh[((t - 1) << 8) | bin], 1u);
        }
      }
    } else {
#pragma unroll
      for (int j = 0; j < 4; ++j) { kk[q * 4 + j] = 0xFFFFFFFFu; tv8[q * 4 + j] = 0; }
    }
  }
  __syncthreads();
  for (int j = tid; j < 1792; j += 256) {
    unsigned v = lh[j];
    if (v) atomicAdd(&ghist[rep + j], v);
  }
  __syncthreads();
  if (tid == 0) sw[4] = (ARRIVE(&stats[77]) == gridDim.x - 1) ? 1u : 0u;
  __syncthreads();
  if (sw[4]) {
    scan_select(stats, ghist, ab, s1, lh);
    if (tid == 0) AS(&stats[38], (s1 == 0) ? 1u : 0u);
    if (s1 > 0)   // atomic stores: plain stores could sit dirty in local L2
      for (int j = tid; j < 14336; j += 256) AS(&ghist[j], 0u);
    __syncthreads();
    if (tid == 0) REL(&stats[39], 1u);
  } else {
    if (tid == 0) while (AL(&stats[39]) < 1u) __builtin_amdgcn_s_sleep(2);
    __syncthreads();
  }
  // ---- rare fallback passes ---------------------------------------------
  if (tid == 0) sw[5] = AL(&stats[38]);
  __syncthreads();
  if (!sw[5]) {
    for (int pass = 2; pass <= 4; ++pass) {
      int sprev = s1 - 8 * (pass - 2); if (sprev < 0) sprev = 0;
      int scur  = s1 - 8 * (pass - 1); if (scur  < 0) scur  = 0;
      unsigned maskhi = 0xFFFFFFFFu << sprev;
      if (tid < 8) sw[8 + tid] = AL(&stats[40 + tid]);
      for (int j = tid; j < 1792; j += 256) lh[j] = 0u;
      __syncthreads();
#pragma unroll
      for (int e = 0; e < 8; ++e) {
        int t = tv8[e];
        if (t && (ab >> t & 1u)) {
          unsigned off = kk[e] - ph0;
          if (((off ^ sw[8 + t]) & maskhi) == 0u)
            atomicAdd(&lh[((t - 1) << 8) | ((off >> scur) & 255u)], 1u);
        }
      }
      __syncthreads();
      for (int j = tid; j < 1792; j += 256) {
        unsigned v = lh[j];
        if (v) atomicAdd(&ghist[rep + j], v);
      }
      __syncthreads();
      if (tid == 0) sw[6] = (ARRIVE(&stats[76 + pass]) == gridDim.x - 1) ? 1u : 0u;
      __syncthreads();
      if (sw[6]) {
        scan_select(stats, ghist, ab, scur, lh);
        if (scur > 0)
          for (int j = tid; j < 14336; j += 256) AS(&ghist[j], 0u);
        __syncthreads();
        if (tid == 0) REL(&stats[39], (unsigned)pass);
      } else {
        if (tid == 0)
          while (AL(&stats[39]) < (unsigned)pass) __builtin_amdgcn_s_sleep(2);
        __syncthreads();
      }
      if (scur == 0) break;
    }
  }
  // ---- median-match counts from register keys ---------------------------
  if (tid < 8) { lh[tid] = 0u; lh[8 + tid] = 0u; sw[20 + tid] = ph0 + AL(&stats[40 + tid]); }
  __syncthreads();
#pragma unroll
  for (int e = 0; e < 8; ++e) {
    unsigned kb = kk[e];
    int t = tv8[e];
#pragma unroll
    for (int tt = 1; tt < 8; ++tt) {
      if ((ab >> tt & 1u) && kb == sw[20 + tt]) {
        atomicAdd(&lh[8 + tt], 1u);
        if (t == tt) atomicAdd(&lh[tt], 1u);
      }
    }
  }
  __syncthreads();
  if (tid >= 1 && tid < 8) {
    if (lh[8 + tid]) atomicAdd(&stats[64 + tid], lh[8 + tid]);   // |full_med|
    if (lh[tid])     atomicAdd(&stats[56 + tid], lh[tid]);       // n11
  }
  __syncthreads();
  if (tid == 0) sw[7] = (ARRIVE(&stats[84]) == gridDim.x - 1) ? 1u : 0u;
  __syncthreads();
  if (!sw[7]) return;
  // ---- finalize (last block) --------------------------------------------
  double vL = 0.0, vI = 0.0, vP = 0.0;
  for (int b = tid; b < nbam; b += 256) {
    vL += pdbl[b * 3]; vI += pdbl[b * 3 + 1]; vP += pdbl[b * 3 + 2];
  }
#pragma unroll
  for (int o = 32; o > 0; o >>= 1) {
    vL += __shfl_down(vL, o); vI += __shfl_down(vI, o); vP += __shfl_down(vP, o);
  }
  int wid = tid >> 6, lane = tid & 63;
  if (lane == 0) { dred[wid] = vL; dred[4 + wid] = vI; dred[8 + wid] = vP; }
  __syncthreads();
  if (tid != 0) return;
  vL = dred[0] + dred[1] + dred[2] + dred[3];
  vI = dred[4] + dred[5] + dred[6] + dred[7];
  vP = dred[8] + dred[9] + dred[10] + dred[11];
  double Nd = (double)N;
  const float e32 = 1e-7f;
  const float c1 = 1.0f - e32;
  const float omc1 = 1.0f - c1;
  double lp1 = log((double)c1);
  double lp0 = log((double)e32);
  double l01 = log((double)omc1);
  double l00 = lp1;
  double L = vL + (double)stats[34] * lp0 + (double)stats[35] * l00;
  double res = -L / Nd;                                               // bce_bg
  res += 1.0 - (2.0 * vI + 1.0) / (vP + (double)stats[8] + 1.0);      // dice_bg
  for (int t = 1; t < 8; ++t) {
    if (ab >> t & 1u) {
      double a = (double)AL(&stats[56 + t]);
      double f = (double)AL(&stats[64 + t]);
      double n = (double)stats[8 + t];
      double bce = -(a * lp1 + (n - a) * lp0 + (f - a) * l01 + (Nd - n - f + a) * l00) / Nd;
      double dice = 1.0 - (2.0 * a + 1.0) / (f + n + 1.0);
      res += bce + dice;
    }
  }
  int nu = (stats[8] > 0) ? 1 : 0;
  for (int t = 1; t < 8; ++t) nu += (stats[8 + t] > 0) ? 1 : 0;
  out[0] = (float)(res / ((double)nu + 1.0));
}

extern "C" void kernel_launch(void* const* d_in, const int* in_sizes, int n_in,
                              void* d_out, int out_size, void* d_ws, size_t ws_size,
                              hipStream_t stream) {
  const float* pred = (const float*)d_in[0];   // [B,8,512,512] f32
  const int* tgt = (const int*)d_in[1];        // [B,1,512,512] i32
  int N = in_sizes[1];                         // B*H*W
  char* ws = (char*)d_ws;
  int* parent = (int*)ws;
  unsigned char* pk = (unsigned char*)(ws + (size_t)N * 4);
  unsigned* stats = (unsigned*)(ws + (size_t)N * 5);
  unsigned* ghist = stats + 8192;
  unsigned* pcnt = stats + 22528;
  double* pdbl = (double*)(stats + 43008);
  float* out = (float*)d_out;
  int nbam = 1024;

  k_argmax<<<nbam, 256, 0, stream>>>(pred, tgt, parent, pk, stats, pcnt, pdbl, N);
  k_uf<<<512, 256, 0, stream>>>(pk, parent, stats, pcnt, N, nbam);
  k_phase2<<<512, 256, 0, stream>>>(pk, parent, stats, ghist, pdbl, out, N, nbam);
}

// Round 11
// 99.565 us; speedup vs baseline: 1.2545x; 1.2545x over previous
//
#include <hip/hip_runtime.h>
#include <math.h>

// ConnectedLossV4, 3-node graph.
// R10 lesson: fusing merge+flatten forced agent-scope (LLC, L1/L2-bypass) ops
// -> k_uf 69.5us at 2.7% VALUBusy. The kernel boundary IS the cheap L2 flush:
// put it between merge (CAS union-find, plain cached ops) and everything that
// reads the final parent[]. Flatten is then just an on-demand root chase with
// plain cached loads inside k_phase2 (parent is read-only there).
//   1 k_argmax  block0 zeros stats+ghist; argmax + continuous bg-bce/dice part;
//               per-block partials via plain stores; parent/pk init.
//   2 k_merge   4-connected min-root CAS union-find. Plain reads (CAS
//               re-verifies at LLC), plain halving stores (target is
//               permanently non-root; value is a persistent ancestor; nothing
//               rewrites parent later -> delayed cross-XCD writeback benign).
//   3 k_phase2  phase A: load parent/pk to REGISTERS, count representatives
//               (parent[i]==i) -> arrive -> last block reduces partials +
//               scalars (AS stores) -> REL; spin. phase B: root chase via
//               PLAIN cached loads (post-boundary fresh), placeholder keys in
//               registers (exact f32 op order), anchored 8-bit radix pass 1
//               into per-(blockIdx&7) ghist replica -> arrive -> last block
//               scans -> REL -> spin -> [rare fallback passes] -> median-match
//               counts from registers -> arrive -> last block bce+dice -> out.
//
// ws layout (N = B*H*W = 1048576):
//   [0,4N) parent | [4N,5N) pk = cls|tgt<<3 | [5N,..) stats/ghist/partials
// stats words: 8..15 cntTarget totals, 16..23 ncomp, 24..31 prodf bits,
//   32 pb, 33 ab, 34 nA, 35 nB, 36 ph0 bits, 37 s1, 38 resolved, 39 radix
//   progress, 40..47 median-offset prefix, 48..55 krem, 56..63 n11, 64..71 nfm,
//   arrivals: 86 phaseA, 77 hist1, 78/79/80 passes, 84 med; flags: 91 scalars.
//   ghist = stats+8192 (8 replicas x 7 x 256 = 14336 words)
//   pcnt  = stats+22528 (1024 blocks x 20 words) ; pdbl = (double*)(stats+43008)

#define HWMASK (262144 - 1)
#define AL(p) __hip_atomic_load((p), __ATOMIC_RELAXED, __HIP_MEMORY_SCOPE_AGENT)
#define AS(p, v) __hip_atomic_store((p), (v), __ATOMIC_RELAXED, __HIP_MEMORY_SCOPE_AGENT)
#define REL(p, v) __hip_atomic_store((p), (v), __ATOMIC_RELEASE, __HIP_MEMORY_SCOPE_AGENT)
#define ARRIVE(p) __hip_atomic_fetch_add((p), 1u, __ATOMIC_RELAXED, __HIP_MEMORY_SCOPE_AGENT)

// Plain ops throughout: stale reads are benign (CAS returns LLC truth and
// retries; halving store target is permanently non-root, stored value is a
// persistent ancestor with g < x). parent[] is not rewritten after this kernel,
// so even delayed cross-XCD writebacks of halving stores are harmless.
static __device__ __forceinline__ int ufind(int* p, int x) {
  while (true) {
    int px = p[x];
    if (px == x) return x;
    int g = p[px];
    if (g == px) return px;
    p[x] = g;  // path halving
    x = g;
  }
}

static __device__ __forceinline__ void unite(int* p, int a, int b) {
  while (true) {
    a = ufind(p, a); b = ufind(p, b);
    if (a == b) return;
    if (a < b) { int old = atomicCAS(&p[b], b, a); if (old == b) return; b = old; }
    else       { int old = atomicCAS(&p[a], a, b); if (old == a) return; a = old; }
  }
}

__global__ __launch_bounds__(256) void k_argmax(
    const float* __restrict__ pred, const int* __restrict__ tgt,
    int* __restrict__ parent, unsigned char* __restrict__ pk,
    unsigned* __restrict__ stats, unsigned* __restrict__ pcnt,
    double* __restrict__ pdbl, int N) {
  __shared__ unsigned hc[32], ht[32], hA, hB;   // per-wave banks (4 waves x 8)
  __shared__ double dred[12];
  int tid = threadIdx.x, bid = blockIdx.x;
  if (bid == 0) {     // zero stats+ghist; no other block touches them here
    uint4* z = (uint4*)stats;
    for (int j = tid; j < 5632; j += 256) z[j] = make_uint4(0u, 0u, 0u, 0u);
  }
  if (tid < 32) { hc[tid] = 0; ht[tid] = 0; }
  if (tid == 0) { hA = 0; hB = 0; }
  __syncthreads();
  int wb = (tid >> 6) << 3;     // wave bank base
  int n4 = N >> 2, gsz = gridDim.x * blockDim.x;
  double aL = 0.0, aI = 0.0, aP = 0.0;
  unsigned nA = 0, nB = 0;
  for (int i4 = bid * blockDim.x + tid; i4 < n4; i4 += gsz) {
    int i = i4 << 2;
    int b = i >> 18, hw = i & HWMASK;
    const float* pp = pred + ((size_t)b << 21) + hw;
    float4 v[8];
#pragma unroll
    for (int ch = 0; ch < 8; ++ch) v[ch] = *(const float4*)(pp + ((size_t)ch << 18));
    int4 tv = *(const int4*)(tgt + i);
    int tarr[4] = {tv.x & 7, tv.y & 7, tv.z & 7, tv.w & 7};
    unsigned char pkb[4];
#pragma unroll
    for (int j = 0; j < 4; ++j) {
      float p0 = ((const float*)&v[0])[j];
      float best = p0; int c = 0;
#pragma unroll
      for (int ch = 1; ch < 8; ++ch) {          // first-max == numpy argmax
        float x = ((const float*)&v[ch])[j];
        if (x > best) { best = x; c = ch; }
      }
      int t = tarr[j];
      pkb[j] = (unsigned char)(c | (t << 3));
      atomicAdd(&hc[wb + c], 1u);
      atomicAdd(&ht[wb + t], 1u);
      if (c == 0) {                             // continuous bg term
        float pc = fminf(fmaxf(p0, 1e-7f), 1.0f - 1e-7f);
        if (t == 0) { aL += (double)logf(pc); aI += (double)p0; }
        else        { aL += (double)logf(1.0f - pc); }
        aP += (double)p0;
      } else { if (t == 0) nA++; else nB++; }   // pv==0 -> constant log, count
    }
    *(int4*)(parent + i) = make_int4(i, i + 1, i + 2, i + 3);
    *(uchar4*)(pk + i) = make_uchar4(pkb[0], pkb[1], pkb[2], pkb[3]);
  }
  if (nA) atomicAdd(&hA, nA);
  if (nB) atomicAdd(&hB, nB);
#pragma unroll
  for (int o = 32; o > 0; o >>= 1) {
    aL += __shfl_down(aL, o); aI += __shfl_down(aI, o); aP += __shfl_down(aP, o);
  }
  int wid = tid >> 6, lane = tid & 63;
  if (lane == 0) { dred[wid] = aL; dred[4 + wid] = aI; dred[8 + wid] = aP; }
  __syncthreads();
  // per-block partials: plain stores, every slot written -> no pre-zero needed
  if (tid < 8) {
    pcnt[bid * 20 + tid]     = hc[tid] + hc[8 + tid] + hc[16 + tid] + hc[24 + tid];
    pcnt[bid * 20 + 8 + tid] = ht[tid] + ht[8 + tid] + ht[16 + tid] + ht[24 + tid];
  }
  if (tid == 0) {
    pcnt[bid * 20 + 16] = hA; pcnt[bid * 20 + 17] = hB;
    pcnt[bid * 20 + 18] = 0u; pcnt[bid * 20 + 19] = 0u;
    pdbl[bid * 3 + 0] = dred[0] + dred[1] + dred[2] + dred[3];
    pdbl[bid * 3 + 1] = dred[4] + dred[5] + dred[6] + dred[7];
    pdbl[bid * 3 + 2] = dred[8] + dred[9] + dred[10] + dred[11];
  }
}

__global__ __launch_bounds__(256) void k_merge(
    const unsigned char* __restrict__ pk, int* __restrict__ parent, int N) {
  int n4 = N >> 2, gsz = gridDim.x * blockDim.x;
  for (int i4 = blockIdx.x * blockDim.x + threadIdx.x; i4 < n4; i4 += gsz) {
    int i = i4 << 2;
    int hw = i & HWMASK;
    uchar4 a = *(const uchar4*)(pk + i);
    unsigned char ca[4] = {(unsigned char)(a.x & 7), (unsigned char)(a.y & 7),
                           (unsigned char)(a.z & 7), (unsigned char)(a.w & 7)};
    if (ca[0] && ca[0] == ca[1]) unite(parent, i,     i + 1);
    if (ca[1] && ca[1] == ca[2]) unite(parent, i + 1, i + 2);
    if (ca[2] && ca[2] == ca[3]) unite(parent, i + 2, i + 3);
    if ((hw & 511) < 508) {                       // quad-boundary, same row
      unsigned char nx = pk[i + 4] & 7;
      if (ca[3] && ca[3] == nx) unite(parent, i + 3, i + 4);
    }
    if ((hw >> 9) < 511) {                        // vertical edges
      uchar4 d = *(const uchar4*)(pk + i + 512);
      unsigned char da[4] = {(unsigned char)(d.x & 7), (unsigned char)(d.y & 7),
                             (unsigned char)(d.z & 7), (unsigned char)(d.w & 7)};
#pragma unroll
      for (int j = 0; j < 4; ++j)
        if (ca[j] && ca[j] == da[j]) unite(parent, i + j, i + j + 512);
    }
  }
}

// Sum 8 ghist replicas, scan 256 bins, pick the bin holding rank krem[t].
static __device__ void scan_select(unsigned* __restrict__ stats,
                                   const unsigned* __restrict__ ghist,
                                   unsigned abm, int s_cur, unsigned* lh) {
  int tid = threadIdx.x;
  for (int t = 1; t < 8; ++t) {
    if (!(abm >> t & 1u)) continue;
    int k = (int)AL(&stats[48 + t]);
    unsigned cnt = 0;
#pragma unroll
    for (int r = 0; r < 8; ++r)
      cnt += AL(&ghist[r * 1792 + ((t - 1) << 8) + tid]);
    lh[tid] = cnt;
    __syncthreads();
    for (int o = 1; o < 256; o <<= 1) {   // inclusive Hillis-Steele
      unsigned v = (tid >= o) ? lh[tid - o] : 0u;
      __syncthreads();
      lh[tid] += v;
      __syncthreads();
    }
    unsigned incl = lh[tid], excl = incl - cnt;
    if ((unsigned)k >= excl && (unsigned)k < incl) {   // unique owner
      atomicOr(&stats[40 + t], ((unsigned)tid) << s_cur);
      AS(&stats[48 + t], (unsigned)(k - (int)excl));
    }
    __syncthreads();
  }
}

__global__ __launch_bounds__(256, 2) void k_phase2(
    const unsigned char* __restrict__ pk, const int* __restrict__ parent,
    unsigned* __restrict__ stats, unsigned* __restrict__ ghist,
    const unsigned* __restrict__ pcnt, const double* __restrict__ pdbl,
    float* __restrict__ out, int N, int nbam) {
  __shared__ unsigned lh[1792];
  __shared__ float sprod[8];
  __shared__ unsigned sw[40], ncs[8], tot[18];
  __shared__ double dred[12];
  int tid = threadIdx.x;
  int n4 = N >> 2, gsz = gridDim.x * blockDim.x;
  // ---- phase A: load parent/pk to registers, count representatives -------
  int parr[8];
  unsigned char pa8[8];
  if (tid < 8) ncs[tid] = 0;
  __syncthreads();
#pragma unroll
  for (int q = 0; q < 2; ++q) {
    int i4 = blockIdx.x * blockDim.x + tid + q * gsz;
    if (i4 < n4) {
      int i = i4 << 2;
      int4 pr = *(const int4*)(parent + i);     // post-boundary fresh
      uchar4 pv = *(const uchar4*)(pk + i);
      parr[q * 4 + 0] = pr.x; parr[q * 4 + 1] = pr.y;
      parr[q * 4 + 2] = pr.z; parr[q * 4 + 3] = pr.w;
      pa8[q * 4 + 0] = pv.x; pa8[q * 4 + 1] = pv.y;
      pa8[q * 4 + 2] = pv.z; pa8[q * 4 + 3] = pv.w;
#pragma unroll
      for (int j = 0; j < 4; ++j) {
        int c = pa8[q * 4 + j] & 7;
        if (c && parr[q * 4 + j] == i + j) atomicAdd(&ncs[c], 1u);
      }
    } else {
#pragma unroll
      for (int j = 0; j < 4; ++j) { parr[q * 4 + j] = -1; pa8[q * 4 + j] = 0; }
    }
  }
  __syncthreads();
  if (tid < 8 && ncs[tid]) atomicAdd(&stats[16 + tid], ncs[tid]);
  __syncthreads();   // drains vmcnt -> this block's ncomp adds at LLC
  if (tid == 0) sw[31] = (ARRIVE(&stats[86]) == gridDim.x - 1) ? 1u : 0u;
  __syncthreads();
  if (sw[31]) {
    // ---- last block: reduce argmax partials + scalars -------------------
    unsigned S[18];
#pragma unroll
    for (int k = 0; k < 18; ++k) S[k] = 0u;
    for (int b = tid; b < nbam; b += 256) {
      const unsigned* p = pcnt + b * 20;
#pragma unroll
      for (int k = 0; k < 18; ++k) S[k] += p[k];
    }
    if (tid < 18) tot[tid] = 0u;
    __syncthreads();
#pragma unroll
    for (int k = 0; k < 18; ++k) {
      unsigned s = S[k];
#pragma unroll
      for (int o = 32; o > 0; o >>= 1) s += __shfl_down(s, o);
      if ((tid & 63) == 0 && s) atomicAdd(&tot[k], s);
    }
    __syncthreads();
    if (tid == 0) {
      float prodf[8]; int last_i = 1; unsigned pb = 0;
      for (int v = 1; v < 8; ++v) {
        unsigned cntv = tot[v], ncv = AL(&stats[16 + v]);
        prodf[v] = 0.0f;
        if (cntv) {
          prodf[v] = __fmul_rn((float)ncv, (float)last_i);   // exact rounding
          pb |= 1u << v;
          last_i += (int)ncv + ((cntv < (unsigned)N) ? 1 : 0);  // + has_bg
        }
        AS(&stats[24 + v], __float_as_uint(prodf[v]));
      }
      float ph0 = 0.0f;   // background key (min key: rounding is monotone)
      for (int v = 1; v < 8; ++v) if (pb & (1u << v)) ph0 = __fadd_rn(ph0, prodf[v]);
      unsigned ab = 0;
      for (int t = 1; t < 8; ++t) {
        unsigned n = tot[8 + t];
        AS(&stats[8 + t], n);
        AS(&stats[48 + t], n ? ((n - 1) >> 1) : 0xFFFFFFFFu);  // lower median
        if (n) ab |= 1u << t;
      }
      AS(&stats[8], tot[8]);
      AS(&stats[34], tot[16]); AS(&stats[35], tot[17]);
      AS(&stats[32], pb); AS(&stats[33], ab);
      unsigned pbits = __float_as_uint(ph0);
      AS(&stats[36], pbits);
      // key-code window: codes in (ph0, ph0+2^20] <= 2^(43-e), e=exp(ph0)
      unsigned c;
      if (pbits == 0) c = 64u;
      else {
        int e = (int)(pbits >> 23) - 127;
        int sh = 43 - e;
        if (sh <= 0) c = 64u;
        else if (sh >= 31) c = 0x7FFFFFFFu;
        else c = (1u << sh) + 64u;
      }
      int bl = 32 - __clz((int)c);
      AS(&stats[37], (bl > 8) ? (unsigned)(bl - 8) : 0u);   // s1, 8-bit digits
      REL(&stats[91], 1u);
    }
  } else {
    if (tid == 0) while (AL(&stats[91]) == 0u) __builtin_amdgcn_s_sleep(2);
    __syncthreads();
  }
  // ---- all blocks: read scalars (AL: they live at LLC) -------------------
  if (tid < 8) sprod[tid] = __uint_as_float(AL(&stats[24 + tid]));
  if (tid == 0) { sw[0] = AL(&stats[32]); sw[1] = AL(&stats[33]);
                  sw[2] = AL(&stats[36]); sw[3] = AL(&stats[37]); }
  for (int j = tid; j < 1792; j += 256) lh[j] = 0u;
  __syncthreads();
  unsigned pb = sw[0], ab = sw[1], ph0 = sw[2];
  int s1 = (int)sw[3];
  unsigned rep = (blockIdx.x & 7) * 1792u;
  // ---- phase B: root chase (plain cached loads) + keys + radix pass 1 ----
  unsigned kk[8];
  unsigned char tv8[8];
#pragma unroll
  for (int q = 0; q < 2; ++q) {
    int i4 = blockIdx.x * blockDim.x + tid + q * gsz;
    if (i4 < n4) {
      int i = i4 << 2;
#pragma unroll
      for (int j = 0; j < 4; ++j) {
        int e = q * 4 + j;
        int c = pa8[e] & 7, t = pa8[e] >> 3;
        float lab = 0.0f;
        if (c) {
          int x = parr[e];
          while (true) { int nx = parent[x]; if (nx == x) break; x = nx; }
          lab = (float)(x + 1);                    // < 2^24, exact
        }
        float ph = 0.0f;
#pragma unroll
        for (int v = 1; v < 8; ++v) {              // exact numpy op order
          if (pb & (1u << v)) {
            float term = sprod[v];
            if (c == v) term = __fadd_rn(lab, term);
            ph = __fadd_rn(ph, term);
          }
        }
        unsigned kb = __float_as_uint(ph);
        kk[e] = kb; tv8[e] = (unsigned char)t;
        if (t && (ab >> t & 1u)) {                 // radix pass 1, anchored
          unsigned off = kb - ph0;                 // >= 0 by monotonicity
          unsigned bin = off >> s1;
          if (bin > 255u) bin = 255u;
          atomicAdd(&lh[((t - 1) << 8) | bin], 1u);
        }
      }
    } else {
#pragma unroll
      for (int j = 0; j < 4; ++j) { kk[q * 4 + j] = 0xFFFFFFFFu; tv8[q * 4 + j] = 0; }
    }
  }
  __syncthreads();
  for (int j = tid; j < 1792; j += 256) {
    unsigned v = lh[j];
    if (v) atomicAdd(&ghist[rep + j], v);
  }
  __syncthreads();
  if (tid == 0) sw[4] = (ARRIVE(&stats[77]) == gridDim.x - 1) ? 1u : 0u;
  __syncthreads();
  if (sw[4]) {
    scan_select(stats, ghist, ab, s1, lh);
    if (tid == 0) AS(&stats[38], (s1 == 0) ? 1u : 0u);
    if (s1 > 0)   // atomic stores: plain stores could sit dirty in local L2
      for (int j = tid; j < 14336; j += 256) AS(&ghist[j], 0u);
    __syncthreads();
    if (tid == 0) REL(&stats[39], 1u);
  } else {
    if (tid == 0) while (AL(&stats[39]) < 1u) __builtin_amdgcn_s_sleep(2);
    __syncthreads();
  }
  // ---- rare fallback passes ---------------------------------------------
  if (tid == 0) sw[5] = AL(&stats[38]);
  __syncthreads();
  if (!sw[5]) {
    for (int pass = 2; pass <= 4; ++pass) {
      int sprev = s1 - 8 * (pass - 2); if (sprev < 0) sprev = 0;
      int scur  = s1 - 8 * (pass - 1); if (scur  < 0) scur  = 0;
      unsigned maskhi = 0xFFFFFFFFu << sprev;
      if (tid < 8) sw[8 + tid] = AL(&stats[40 + tid]);
      for (int j = tid; j < 1792; j += 256) lh[j] = 0u;
      __syncthreads();
#pragma unroll
      for (int e = 0; e < 8; ++e) {
        int t = tv8[e];
        if (t && (ab >> t & 1u)) {
          unsigned off = kk[e] - ph0;
          if (((off ^ sw[8 + t]) & maskhi) == 0u)
            atomicAdd(&lh[((t - 1) << 8) | ((off >> scur) & 255u)], 1u);
        }
      }
      __syncthreads();
      for (int j = tid; j < 1792; j += 256) {
        unsigned v = lh[j];
        if (v) atomicAdd(&ghist[rep + j], v);
      }
      __syncthreads();
      if (tid == 0) sw[6] = (ARRIVE(&stats[76 + pass]) == gridDim.x - 1) ? 1u : 0u;
      __syncthreads();
      if (sw[6]) {
        scan_select(stats, ghist, ab, scur, lh);
        if (scur > 0)
          for (int j = tid; j < 14336; j += 256) AS(&ghist[j], 0u);
        __syncthreads();
        if (tid == 0) REL(&stats[39], (unsigned)pass);
      } else {
        if (tid == 0)
          while (AL(&stats[39]) < (unsigned)pass) __builtin_amdgcn_s_sleep(2);
        __syncthreads();
      }
      if (scur == 0) break;
    }
  }
  // ---- median-match counts from register keys ---------------------------
  if (tid < 8) { lh[tid] = 0u; lh[8 + tid] = 0u; sw[20 + tid] = ph0 + AL(&stats[40 + tid]); }
  __syncthreads();
#pragma unroll
  for (int e = 0; e < 8; ++e) {
    unsigned kb = kk[e];
    int t = tv8[e];
#pragma unroll
    for (int tt = 1; tt < 8; ++tt) {
      if ((ab >> tt & 1u) && kb == sw[20 + tt]) {
        atomicAdd(&lh[8 + tt], 1u);
        if (t == tt) atomicAdd(&lh[tt], 1u);
      }
    }
  }
  __syncthreads();
  if (tid >= 1 && tid < 8) {
    if (lh[8 + tid]) atomicAdd(&stats[64 + tid], lh[8 + tid]);   // |full_med|
    if (lh[tid])     atomicAdd(&stats[56 + tid], lh[tid]);       // n11
  }
  __syncthreads();
  if (tid == 0) sw[7] = (ARRIVE(&stats[84]) == gridDim.x - 1) ? 1u : 0u;
  __syncthreads();
  if (!sw[7]) return;
  // ---- finalize (last block) --------------------------------------------
  double vL = 0.0, vI = 0.0, vP = 0.0;
  for (int b = tid; b < nbam; b += 256) {
    vL += pdbl[b * 3]; vI += pdbl[b * 3 + 1]; vP += pdbl[b * 3 + 2];
  }
#pragma unroll
  for (int o = 32; o > 0; o >>= 1) {
    vL += __shfl_down(vL, o); vI += __shfl_down(vI, o); vP += __shfl_down(vP, o);
  }
  int wid = tid >> 6, lane = tid & 63;
  if (lane == 0) { dred[wid] = vL; dred[4 + wid] = vI; dred[8 + wid] = vP; }
  __syncthreads();
  if (tid != 0) return;
  vL = dred[0] + dred[1] + dred[2] + dred[3];
  vI = dred[4] + dred[5] + dred[6] + dred[7];
  vP = dred[8] + dred[9] + dred[10] + dred[11];
  double Nd = (double)N;
  const float e32 = 1e-7f;
  const float c1 = 1.0f - e32;
  const float omc1 = 1.0f - c1;
  double lp1 = log((double)c1);
  double lp0 = log((double)e32);
  double l01 = log((double)omc1);
  double l00 = lp1;
  double L = vL + (double)AL(&stats[34]) * lp0 + (double)AL(&stats[35]) * l00;
  double res = -L / Nd;                                                  // bce_bg
  res += 1.0 - (2.0 * vI + 1.0) / (vP + (double)AL(&stats[8]) + 1.0);    // dice_bg
  for (int t = 1; t < 8; ++t) {
    if (ab >> t & 1u) {
      double a = (double)AL(&stats[56 + t]);
      double f = (double)AL(&stats[64 + t]);
      double n = (double)AL(&stats[8 + t]);
      double bce = -(a * lp1 + (n - a) * lp0 + (f - a) * l01 + (Nd - n - f + a) * l00) / Nd;
      double dice = 1.0 - (2.0 * a + 1.0) / (f + n + 1.0);
      res += bce + dice;
    }
  }
  int nu = (AL(&stats[8]) > 0) ? 1 : 0;
  for (int t = 1; t < 8; ++t) nu += (AL(&stats[8 + t]) > 0) ? 1 : 0;
  out[0] = (float)(res / ((double)nu + 1.0));
}

extern "C" void kernel_launch(void* const* d_in, const int* in_sizes, int n_in,
                              void* d_out, int out_size, void* d_ws, size_t ws_size,
                              hipStream_t stream) {
  const float* pred = (const float*)d_in[0];   // [B,8,512,512] f32
  const int* tgt = (const int*)d_in[1];        // [B,1,512,512] i32
  int N = in_sizes[1];                         // B*H*W
  char* ws = (char*)d_ws;
  int* parent = (int*)ws;
  unsigned char* pk = (unsigned char*)(ws + (size_t)N * 4);
  unsigned* stats = (unsigned*)(ws + (size_t)N * 5);
  unsigned* ghist = stats + 8192;
  unsigned* pcnt = stats + 22528;
  double* pdbl = (double*)(stats + 43008);
  float* out = (float*)d_out;
  int nbam = 1024;

  k_argmax<<<nbam, 256, 0, stream>>>(pred, tgt, parent, pk, stats, pcnt, pdbl, N);
  k_merge<<<nbam, 256, 0, stream>>>(pk, parent, N);
  k_phase2<<<512, 256, 0, stream>>>(pk, parent, stats, ghist, pcnt, pdbl, out, N, nbam);
}